// Round 2
// baseline (38.105 us; speedup 1.0000x reference)
//
#include <hip/hip_runtime.h>

// Problem constants (fixed by reference: INPUT_SHAPE=(1,3,48,48), stride=2, pad=1)
#define OC   16
#define IC   3
#define KH   4
#define KW   4
#define IH   48
#define IW   48
#define STR  2
#define PAD  1
#define HO   24          // (48 + 2*1 - 4)/2 + 1
#define WO   24
#define NCOL (IC*IH*IW)  // 6912 flattened input size
#define NROW (OC*HO*WO)  // 9216 flattened output size
#define NC4  (NCOL/4)    // 1728 float4 per W row
#define WTOT4 (NROW * NC4)            // 15,925,248 float4s of W_mat
#define TOT4  (WTOT4 + NROW / 4)      // + 2304 float4s of bias tail

// One flat grid-stride kernel: W_mat float4s [0, WTOT4), bias float4s after.
// Each bias float4 covers 4 consecutive rows; 576 % 4 == 0 so all 4 share o.
__global__ void __launch_bounds__(256)
deeppoly_fused_kernel(const float* __restrict__ kern,
                      const float* __restrict__ bias,
                      float* __restrict__ out) {
    const int stride = gridDim.x * blockDim.x;
    for (int i = blockIdx.x * blockDim.x + threadIdx.x; i < TOT4; i += stride) {
        float4 v = make_float4(0.f, 0.f, 0.f, 0.f);
        if (i < WTOT4) {
            int row = i / NC4;                    // magic-mul
            int c4  = i - row * NC4;
            int o   = row / (HO * WO);
            int rem = row - o * (HO * WO);
            int oh  = rem / WO;
            int ow  = rem - oh * WO;

            int c  = c4 / (IH * IW / 4);          // / 576
            int r2 = c4 - c * (IH * IW / 4);
            int h  = r2 / (IW / 4);               // / 12
            int w0 = (r2 - h * (IW / 4)) * 4;

            int kh = h - (oh * STR - PAD);
            if (kh >= 0 && kh < KH) {
                int kwb = w0 - (ow * STR - PAD);
                const float* kp = kern + ((o * IC + c) * KH + kh) * KW;
                float x[4];
#pragma unroll
                for (int j = 0; j < 4; ++j) {
                    int kw = kwb + j;
                    x[j] = (kw >= 0 && kw < KW) ? kp[kw] : 0.f;
                }
                v = make_float4(x[0], x[1], x[2], x[3]);
            }
        } else {
            int r = (i - WTOT4) * 4;              // first of 4 rows, same o
            float b = bias[r / (HO * WO)];
            v = make_float4(b, b, b, b);
        }
        reinterpret_cast<float4*>(out)[i] = v;
    }
}

extern "C" void kernel_launch(void* const* d_in, const int* in_sizes, int n_in,
                              void* d_out, int out_size, void* d_ws, size_t ws_size,
                              hipStream_t stream) {
    const float* kern = (const float*)d_in[0];   // (16,3,4,4) f32
    const float* bias = (const float*)d_in[1];   // (16,)      f32
    float* out = (float*)d_out;                  // 9216*6912 + 9216 floats

    const int block = 256;
    int grid = (TOT4 + block - 1) / block;
    if (grid > 2048) grid = 2048;                // grid-stride the rest
    deeppoly_fused_kernel<<<grid, block, 0, stream>>>(kern, bias, out);
}